// Round 6
// baseline (943.692 us; speedup 1.0000x reference)
//
#include <hip/hip_runtime.h>
#include <hip/hip_fp16.h>

// Sizes fixed by the reference.
#define BB 2
#define HH 16
#define SS 2048
#define DD 128

typedef __attribute__((ext_vector_type(8))) _Float16 f16x8;
typedef __attribute__((ext_vector_type(4))) float    f32x4;

// k_norm = k / max(||k||_2 over HEAD axis, eps), cast to f16.
__global__ void knorm_f16(const float* __restrict__ k, _Float16* __restrict__ kh) {
  int t = blockIdx.x * 256 + threadIdx.x;      // [0, B*S*D)
  int d = t & (DD - 1);
  int s = (t >> 7) & (SS - 1);
  int b = t >> 18;                              // S*D = 2^18
  const float* kp = k + (size_t)b * HH * SS * DD + (size_t)s * DD + d;
  float vals[HH];
  float ss = 0.f;
  #pragma unroll
  for (int h = 0; h < HH; ++h) { float x = kp[(size_t)h * SS * DD]; vals[h] = x; ss += x * x; }
  float r = 1.0f / fmaxf(sqrtf(ss), 1e-12f);
  _Float16* op = kh + (size_t)b * HH * SS * DD + (size_t)s * DD + d;
  #pragma unroll
  for (int h = 0; h < HH; ++h) op[(size_t)h * SS * DD] = (_Float16)(vals[h] * r);
}

// q -> f16, 8 elements/thread.
__global__ void cvt_f16(const float* __restrict__ x, _Float16* __restrict__ y) {
  size_t i = ((size_t)blockIdx.x * 256 + threadIdx.x) * 8;
  float4 a = *(const float4*)(x + i);
  float4 b = *(const float4*)(x + i + 4);
  f16x8 r = { (_Float16)a.x, (_Float16)a.y, (_Float16)a.z, (_Float16)a.w,
              (_Float16)b.x, (_Float16)b.y, (_Float16)b.z, (_Float16)b.w };
  *(f16x8*)(y + i) = r;
}

// v[b,h,s,d] -> vt[b,h,d,s] as f16 (PV B-operand: 8 contiguous keys at fixed d).
__global__ void vtrans_f16(const float* __restrict__ v, _Float16* __restrict__ vt) {
  __shared__ float tile[32][33];
  int bh = blockIdx.z;
  int d0 = blockIdx.x * 32, s0 = blockIdx.y * 32;
  const float* vp = v + (size_t)bh * SS * DD;
  _Float16* tp = vt + (size_t)bh * SS * DD;
  int tx = threadIdx.x, ty = threadIdx.y;       // block (32,8)
  #pragma unroll
  for (int i = ty; i < 32; i += 8)
    tile[i][tx] = vp[(size_t)(s0 + i) * DD + d0 + tx];
  __syncthreads();
  #pragma unroll
  for (int i = ty; i < 32; i += 8)
    tp[(size_t)(d0 + i) * SS + s0 + tx] = (_Float16)tile[tx][i];
}

// ---------------- Kernel A: scores + mask + softmax + attn(f32) store -------
// RECOMPUTE structure: pass 1 accumulates denom = sum(exp(s)) holding only one
// 4-reg MFMA tile; pass 2 recomputes s and stores exp(s)*inv. No max pass
// (scores bounded: exp(s) <= ~1e13 fits f32; masked -> exact 0). Live set
// ~45 regs -> a true 8 waves/SIMD with NO spill (r5's acc[16] spilled 540 MB
// of scratch under the 64-reg budget; r4's acc[8] capped occupancy at 50%).
// WG = 512 thr (8 waves), QBLK=32. Wave w: q-half (w>>2), key-quarter (w&3).
__global__ __launch_bounds__(512, 8) void scores_f16(
    const _Float16* __restrict__ qh, const _Float16* __restrict__ kh,
    const int* __restrict__ mask, float* __restrict__ attn)
{
  __shared__ float redsum[2][16][5];   // [q-half][q][key-quarter], padded

  // XCD swizzle: wgid%8 = XCD; each XCD owns 4 heads, walks their q-tiles.
  const int wgid = blockIdx.x;                  // [0, 2048)
  const int xcd  = wgid & 7;
  const int idx  = wgid >> 3;                   // [0, 256)
  const int bh   = (xcd << 2) | (idx >> 6);     // 4 heads per XCD
  const int q0   = (idx & 63) * 32;
  const int b    = bh >> 4;

  const int lane = threadIdx.x & 63;
  const int w    = threadIdx.x >> 6;            // [0,8)
  const int qh2  = w >> 2;                      // q-half
  const int kq   = w & 3;                       // key-quarter (512 keys)
  const int lo16 = lane & 15;
  const int g    = lane >> 4;

  const size_t hoff = (size_t)bh * SS * DD;
  const _Float16* Q = qh + hoff + (size_t)(q0 + qh2 * 16) * DD;
  const _Float16* K = kh + hoff;
  const int* mrow = mask + b * SS;

  // Q fragments (B operand): lane holds Q[row=lo16][c*32+g*8 .. +7]
  f16x8 qf[4];
  #pragma unroll
  for (int c = 0; c < 4; ++c)
    qf[c] = *(const f16x8*)(Q + lo16 * DD + c * 32 + g * 8);

  // ---- pass 1: denominator (no score storage) ----
  float sum = 0.f;
  #pragma unroll 8
  for (int kt = 0; kt < 32; ++kt) {
    const int key0 = kq * 512 + kt * 16;
    f32x4 a = {0.f, 0.f, 0.f, 0.f};
    #pragma unroll
    for (int c = 0; c < 4; ++c) {
      f16x8 kf = *(const f16x8*)(K + (size_t)(key0 + lo16) * DD + c * 32 + g * 8);
      a = __builtin_amdgcn_mfma_f32_16x16x32_f16(kf, qf[c], a, 0, 0, 0);
    }
    const int4 mv = *(const int4*)(mrow + key0 + g * 4);
    sum += mv.x ? __expf(a[0]) : 0.f;
    sum += mv.y ? __expf(a[1]) : 0.f;
    sum += mv.z ? __expf(a[2]) : 0.f;
    sum += mv.w ? __expf(a[3]) : 0.f;
  }
  sum += __shfl_xor(sum, 16);
  sum += __shfl_xor(sum, 32);
  if (lane < 16) redsum[qh2][lane][kq] = sum;
  __syncthreads();
  const float inv = 1.0f / (redsum[qh2][lo16][0] + redsum[qh2][lo16][1] +
                            redsum[qh2][lo16][2] + redsum[qh2][lo16][3]);

  // ---- pass 2: recompute scores, store normalized attn (f32) ----
  float* arow = attn + ((size_t)bh * SS + q0 + qh2 * 16 + lo16) * SS;
  #pragma unroll 8
  for (int kt = 0; kt < 32; ++kt) {
    const int key0 = kq * 512 + kt * 16;
    f32x4 a = {0.f, 0.f, 0.f, 0.f};
    #pragma unroll
    for (int c = 0; c < 4; ++c) {
      f16x8 kf = *(const f16x8*)(K + (size_t)(key0 + lo16) * DD + c * 32 + g * 8);
      a = __builtin_amdgcn_mfma_f32_16x16x32_f16(kf, qf[c], a, 0, 0, 0);
    }
    const int4 mv = *(const int4*)(mrow + key0 + g * 4);
    f32x4 p = { mv.x ? __expf(a[0]) * inv : 0.f,
                mv.y ? __expf(a[1]) * inv : 0.f,
                mv.z ? __expf(a[2]) * inv : 0.f,
                mv.w ? __expf(a[3]) * inv : 0.f };
    *(f32x4*)(arow + key0 + g * 4) = p;   // 4 g-groups x 16B = full 64B lines
  }
}

// ---------------- Kernel B: out = attn @ v ---------------------------------
// WG = 256 thr (4 waves): 32 q-rows x full D=128 per block; wave w: q-sub
// (w&1)*16, d-half (w>>1)*64. 2-stage register pipeline (static indices).
// bound (256,4): live ~81 regs -> budget 128, NO spill (r5's (256,8) spilled).
__global__ __launch_bounds__(256, 4) void pv_f16(
    const float* __restrict__ attn, const _Float16* __restrict__ vth,
    float* __restrict__ out)
{
  const int wgid = blockIdx.x;                  // [0, 2048)
  const int xcd  = wgid & 7;
  const int idx  = wgid >> 3;                   // [0, 256)
  const int bh   = (xcd << 2) | (idx >> 6);     // same head->XCD map as A
  const int q0   = (idx & 63) * 32;

  const int lane = threadIdx.x & 63;
  const int w    = threadIdx.x >> 6;            // [0,4)
  const int qs   = (w & 1) * 16;
  const int dh   = (w >> 1) * 64;
  const int lo16 = lane & 15;
  const int g    = lane >> 4;

  const size_t hoff = (size_t)bh * SS * DD;
  const float* A = attn + ((size_t)bh * SS + q0 + qs + lo16) * SS + g * 8;
  const _Float16* V = vth + hoff + (size_t)(dh + lo16) * SS + g * 8;

  f32x4 pa0[2], pa1[2];
  f16x8 pv0[2], pv1[2], pv2[2], pv3[2];

  // prologue: stage kt=0
  pa0[0] = *(const f32x4*)(A);
  pa1[0] = *(const f32x4*)(A + 4);
  pv0[0] = *(const f16x8*)(V);
  pv1[0] = *(const f16x8*)(V + (size_t)16 * SS);
  pv2[0] = *(const f16x8*)(V + (size_t)32 * SS);
  pv3[0] = *(const f16x8*)(V + (size_t)48 * SS);

  f32x4 oacc[4] = { {0,0,0,0}, {0,0,0,0}, {0,0,0,0}, {0,0,0,0} };

  #pragma unroll
  for (int kt = 0; kt < 64; ++kt) {
    const int cur = kt & 1, nxt = cur ^ 1;
    if (kt < 63) {
      const int k1 = (kt + 1) * 32;
      pa0[nxt] = *(const f32x4*)(A + k1);
      pa1[nxt] = *(const f32x4*)(A + k1 + 4);
      pv0[nxt] = *(const f16x8*)(V + k1);
      pv1[nxt] = *(const f16x8*)(V + (size_t)16 * SS + k1);
      pv2[nxt] = *(const f16x8*)(V + (size_t)32 * SS + k1);
      pv3[nxt] = *(const f16x8*)(V + (size_t)48 * SS + k1);
    }
    f16x8 pf = { (_Float16)pa0[cur][0], (_Float16)pa0[cur][1],
                 (_Float16)pa0[cur][2], (_Float16)pa0[cur][3],
                 (_Float16)pa1[cur][0], (_Float16)pa1[cur][1],
                 (_Float16)pa1[cur][2], (_Float16)pa1[cur][3] };
    oacc[0] = __builtin_amdgcn_mfma_f32_16x16x32_f16(pf, pv0[cur], oacc[0], 0, 0, 0);
    oacc[1] = __builtin_amdgcn_mfma_f32_16x16x32_f16(pf, pv1[cur], oacc[1], 0, 0, 0);
    oacc[2] = __builtin_amdgcn_mfma_f32_16x16x32_f16(pf, pv2[cur], oacc[2], 0, 0, 0);
    oacc[3] = __builtin_amdgcn_mfma_f32_16x16x32_f16(pf, pv3[cur], oacc[3], 0, 0, 0);
  }

  float* O = out + hoff + (size_t)(q0 + qs) * DD + dh;
  #pragma unroll
  for (int t = 0; t < 4; ++t) {
    #pragma unroll
    for (int i = 0; i < 4; ++i) {
      const int qrow = g * 4 + i;               // C row = q, col = d
      O[(size_t)qrow * DD + t * 16 + lo16] = oacc[t][i];
    }
  }
}

extern "C" void kernel_launch(void* const* d_in, const int* in_sizes, int n_in,
                              void* d_out, int out_size, void* d_ws, size_t ws_size,
                              hipStream_t stream) {
  const float* q    = (const float*)d_in[0];
  const float* k    = (const float*)d_in[1];
  const float* v    = (const float*)d_in[2];
  const int*   mask = (const int*)d_in[3];

  const size_t N = (size_t)BB * HH * SS * DD;     // 8388608
  float* out  = (float*)d_out;
  float* attn = out + N;                          // outputs concatenated (out, attn)

  // scratch: 3 f16 tensors = 48 MB
  _Float16* qh  = (_Float16*)d_ws;
  _Float16* kh  = qh + N;
  _Float16* vth = kh + N;

  cvt_f16  <<<N / 8 / 256, 256, 0, stream>>>(q, qh);
  knorm_f16<<<(BB * SS * DD) / 256, 256, 0, stream>>>(k, kh);
  vtrans_f16<<<dim3(DD / 32, SS / 32, BB * HH), dim3(32, 8), 0, stream>>>(v, vth);

  scores_f16<<<2048, 512, 0, stream>>>(qh, kh, mask, attn);
  pv_f16    <<<2048, 256, 0, stream>>>(attn, vth, out);
}

// Round 7
// 644.876 us; speedup vs baseline: 1.4634x; 1.4634x over previous
//
#include <hip/hip_runtime.h>
#include <hip/hip_fp16.h>

// Sizes fixed by the reference.
#define BB 2
#define HH 16
#define SS 2048
#define DD 128

typedef __attribute__((ext_vector_type(8))) _Float16 f16x8;
typedef __attribute__((ext_vector_type(4))) _Float16 f16x4;
typedef __attribute__((ext_vector_type(4))) float    f32x4;

// XOR swizzle for [16][2048] f16 LDS tile (row stride 4096 B). Flip octet
// index with row&7 -> bank-spread b128/b64 accesses (r1-verified pattern).
__device__ __forceinline__ int swz(int row, int k) {
  return row * SS + (k ^ ((row & 7) << 3));
}

// k_norm = k / max(||k||_2 over HEAD axis, eps), cast to f16.
__global__ void knorm_f16(const float* __restrict__ k, _Float16* __restrict__ kh) {
  int t = blockIdx.x * 256 + threadIdx.x;      // [0, B*S*D)
  int d = t & (DD - 1);
  int s = (t >> 7) & (SS - 1);
  int b = t >> 18;                              // S*D = 2^18
  const float* kp = k + (size_t)b * HH * SS * DD + (size_t)s * DD + d;
  float vals[HH];
  float ss = 0.f;
  #pragma unroll
  for (int h = 0; h < HH; ++h) { float x = kp[(size_t)h * SS * DD]; vals[h] = x; ss += x * x; }
  float r = 1.0f / fmaxf(sqrtf(ss), 1e-12f);
  _Float16* op = kh + (size_t)b * HH * SS * DD + (size_t)s * DD + d;
  #pragma unroll
  for (int h = 0; h < HH; ++h) op[(size_t)h * SS * DD] = (_Float16)(vals[h] * r);
}

// q -> f16, 8 elements/thread.
__global__ void cvt_f16(const float* __restrict__ x, _Float16* __restrict__ y) {
  size_t i = ((size_t)blockIdx.x * 256 + threadIdx.x) * 8;
  float4 a = *(const float4*)(x + i);
  float4 b = *(const float4*)(x + i + 4);
  f16x8 r = { (_Float16)a.x, (_Float16)a.y, (_Float16)a.z, (_Float16)a.w,
              (_Float16)b.x, (_Float16)b.y, (_Float16)b.z, (_Float16)b.w };
  *(f16x8*)(y + i) = r;
}

// v[b,h,s,d] -> vt[b,h,d,s] as f16 (PV B-operand: 8 contiguous keys at fixed d).
__global__ void vtrans_f16(const float* __restrict__ v, _Float16* __restrict__ vt) {
  __shared__ float tile[32][33];
  int bh = blockIdx.z;
  int d0 = blockIdx.x * 32, s0 = blockIdx.y * 32;
  const float* vp = v + (size_t)bh * SS * DD;
  _Float16* tp = vt + (size_t)bh * SS * DD;
  int tx = threadIdx.x, ty = threadIdx.y;       // block (32,8)
  #pragma unroll
  for (int i = ty; i < 32; i += 8)
    tile[i][tx] = vp[(size_t)(s0 + i) * DD + d0 + tx];
  __syncthreads();
  #pragma unroll
  for (int i = ty; i < 32; i += 8)
    tp[(size_t)(d0 + i) * SS + s0 + tx] = (_Float16)tile[tx][i];
}

// ---------------- Fused attention (r7) --------------------------------------
// QBLK=16, 1024 thr (16 waves). Phase 1: wave w owns keys [w*128,+128) with
// acc[8] = 32 accum regs (r4's proven no-spill score config, 388 us).
// Phase 2: sum-only softmax (no max pass: |s| <~ 16 so exp(s) is f32-safe;
// masked keys are exact 0) -> P as f16 into swizzled LDS.
// Phase 3 (no further barriers, concurrent wave jobs):
//   waves 0-7 : PV MFMA from LDS P + L2-resident V^T -> out
//   waves 8-15: coalesced f32 attn write from LDS (2 KB/instr)
// This deletes the separate pv kernel and its 537 MB attn re-read.
__global__ __launch_bounds__(1024, 4) void attn_fused(
    const _Float16* __restrict__ qh, const _Float16* __restrict__ kh,
    const _Float16* __restrict__ vth, const int* __restrict__ mask,
    float* __restrict__ out, float* __restrict__ attn)
{
  __shared__ _Float16 sc[16 * SS];     // P, [q][key] swizzled, 64 KB
  __shared__ float redsum[16][17];     // [q][wave], padded

  // XCD swizzle: wgid%8 = XCD; each XCD owns 4 heads, walks their q-tiles.
  const int wgid = blockIdx.x;                  // [0, 4096)
  const int xcd  = wgid & 7;
  const int idx  = wgid >> 3;                   // [0, 512)
  const int bh   = (xcd << 2) | (idx >> 7);     // 4 heads per XCD
  const int q0   = (idx & 127) * 16;
  const int b    = bh >> 4;

  const int lane = threadIdx.x & 63;
  const int w    = threadIdx.x >> 6;            // [0,16)
  const int lo16 = lane & 15;
  const int g    = lane >> 4;

  const size_t hoff = (size_t)bh * SS * DD;
  const _Float16* Q = qh + hoff + (size_t)q0 * DD;
  const _Float16* K = kh + hoff;
  const _Float16* V = vth + hoff;               // [D][S]
  const int* mrow = mask + b * SS;

  // Q fragments (B operand): lane holds Q[q0+lo16][c*32+g*8 .. +7]
  f16x8 qf[4];
  #pragma unroll
  for (int c = 0; c < 4; ++c)
    qf[c] = *(const f16x8*)(Q + lo16 * DD + c * 32 + g * 8);

  // ---- Phase 1: E = exp(scores) for this wave's 128 keys (masked -> 0) ----
  f32x4 acc[8];
  float ssum = 0.f;
  #pragma unroll
  for (int kt = 0; kt < 8; ++kt) {
    const int key0 = w * 128 + kt * 16;
    f32x4 a = {0.f, 0.f, 0.f, 0.f};
    #pragma unroll
    for (int c = 0; c < 4; ++c) {
      f16x8 kf = *(const f16x8*)(K + (size_t)(key0 + lo16) * DD + c * 32 + g * 8);
      a = __builtin_amdgcn_mfma_f32_16x16x32_f16(kf, qf[c], a, 0, 0, 0);
    }
    // C layout: col(q)=lane&15, row(key)=g*4+i
    const int4 mv = *(const int4*)(mrow + key0 + g * 4);
    a[0] = mv.x ? __expf(a[0]) : 0.f;
    a[1] = mv.y ? __expf(a[1]) : 0.f;
    a[2] = mv.z ? __expf(a[2]) : 0.f;
    a[3] = mv.w ? __expf(a[3]) : 0.f;
    ssum += a[0] + a[1] + a[2] + a[3];
    acc[kt] = a;
  }

  // ---- Phase 2: denominator + P(f16) into swizzled LDS ----
  ssum += __shfl_xor(ssum, 16);
  ssum += __shfl_xor(ssum, 32);
  if (lane < 16) redsum[lane][w] = ssum;
  __syncthreads();
  float denom = 0.f;
  #pragma unroll
  for (int j = 0; j < 16; ++j) denom += redsum[lo16][j];
  const float inv = 1.0f / denom;

  #pragma unroll
  for (int kt = 0; kt < 8; ++kt) {
    const int kbase = w * 128 + kt * 16 + g * 4;
    f16x4 ph = { (_Float16)(acc[kt][0] * inv), (_Float16)(acc[kt][1] * inv),
                 (_Float16)(acc[kt][2] * inv), (_Float16)(acc[kt][3] * inv) };
    *(f16x4*)(&sc[swz(lo16, kbase)]) = ph;
  }
  __syncthreads();

  if (w < 8) {
    // ---- Phase 3a (waves 0-7): PV. Wave owns d-cols [w*16, w*16+16). ----
    const int dcol = w * 16;
    f32x4 oacc = {0.f, 0.f, 0.f, 0.f};
    #pragma unroll 8
    for (int kt = 0; kt < 64; ++kt) {
      const int k0 = kt * 32;
      f16x8 pf = *(const f16x8*)(&sc[swz(lo16, k0 + g * 8)]);  // A: P[q][k..]
      f16x8 vf = *(const f16x8*)(V + (size_t)(dcol + lo16) * SS + k0 + g * 8);
      oacc = __builtin_amdgcn_mfma_f32_16x16x32_f16(pf, vf, oacc, 0, 0, 0);
    }
    float* O = out + hoff + (size_t)q0 * DD + dcol;
    #pragma unroll
    for (int i = 0; i < 4; ++i) {
      const int qrow = g * 4 + i;               // C row = q, col = d
      O[(size_t)qrow * DD + lo16] = oacc[i];
    }
  } else {
    // ---- Phase 3b (waves 8-15): coalesced f32 attn write, 2 rows/wave ----
    #pragma unroll
    for (int rr = 0; rr < 2; ++rr) {
      const int row = (w - 8) * 2 + rr;
      float* arow = attn + ((size_t)bh * SS + q0 + row) * SS;
      #pragma unroll
      for (int c = 0; c < 4; ++c) {
        const int kk = c * 512 + lane * 8;
        f16x8 p8 = *(const f16x8*)(&sc[swz(row, kk)]);
        float4 lo = { (float)p8[0], (float)p8[1], (float)p8[2], (float)p8[3] };
        float4 hi = { (float)p8[4], (float)p8[5], (float)p8[6], (float)p8[7] };
        *(float4*)(arow + kk)     = lo;
        *(float4*)(arow + kk + 4) = hi;
      }
    }
  }
}

extern "C" void kernel_launch(void* const* d_in, const int* in_sizes, int n_in,
                              void* d_out, int out_size, void* d_ws, size_t ws_size,
                              hipStream_t stream) {
  const float* q    = (const float*)d_in[0];
  const float* k    = (const float*)d_in[1];
  const float* v    = (const float*)d_in[2];
  const int*   mask = (const int*)d_in[3];

  const size_t N = (size_t)BB * HH * SS * DD;     // 8388608
  float* out  = (float*)d_out;
  float* attn = out + N;                          // outputs concatenated (out, attn)

  // scratch: 3 f16 tensors = 48 MB
  _Float16* qh  = (_Float16*)d_ws;
  _Float16* kh  = qh + N;
  _Float16* vth = kh + N;

  cvt_f16  <<<N / 8 / 256, 256, 0, stream>>>(q, qh);
  knorm_f16<<<(BB * SS * DD) / 256, 256, 0, stream>>>(k, kh);
  vtrans_f16<<<dim3(DD / 32, SS / 32, BB * HH), dim3(32, 8), 0, stream>>>(v, vth);

  attn_fused<<<4096, 1024, 0, stream>>>(qh, kh, vth, mask, out, attn);
}

// Round 8
// 452.470 us; speedup vs baseline: 2.0856x; 1.4252x over previous
//
#include <hip/hip_runtime.h>
#include <hip/hip_fp16.h>

// Sizes fixed by the reference.
#define BB 2
#define HH 16
#define SS 2048
#define DD 128
#define CHUNK 128          // keys per staged K/V chunk (32 KB f16)
#define NCHUNK 16          // SS / CHUNK

typedef __attribute__((ext_vector_type(8))) _Float16 f16x8;
typedef __attribute__((ext_vector_type(4))) _Float16 f16x4;
typedef __attribute__((ext_vector_type(4))) float    f32x4;

// P-store swizzle in LDS: element (row,k) lives at row*SS + (k ^ ((row&7)<<3)).
__device__ __forceinline__ int swz(int row, int k) {
  return row * SS + (k ^ ((row & 7) << 3));
}

__device__ __forceinline__ void load_lds16(const void* g, void* l) {
  __builtin_amdgcn_global_load_lds(
      (const __attribute__((address_space(1))) void*)g,
      (__attribute__((address_space(3))) void*)l, 16, 0, 0);
}

__device__ __forceinline__ void block_barrier() {
  asm volatile("" ::: "memory");
  __builtin_amdgcn_s_barrier();
  asm volatile("" ::: "memory");
}

// k_norm = k / max(||k||_2 over HEAD axis, eps), cast to f16, stored in a
// PRE-SWIZZLED row layout: element (s,d) at s*128 + (((d>>3)^(s&7))<<3)+(d&7).
// Linear global_load_lds of a 128-key chunk then yields an LDS image whose
// 16B slot p of row r holds d-group p^(r&7)  -> conflict-free fragment reads.
__global__ void knorm_f16(const float* __restrict__ k, _Float16* __restrict__ kh) {
  int t = blockIdx.x * 256 + threadIdx.x;      // [0, B*S*D)
  int d = t & (DD - 1);
  int s = (t >> 7) & (SS - 1);
  int b = t >> 18;                              // S*D = 2^18
  const float* kp = k + (size_t)b * HH * SS * DD + (size_t)s * DD + d;
  float vals[HH];
  float ss = 0.f;
  #pragma unroll
  for (int h = 0; h < HH; ++h) { float x = kp[(size_t)h * SS * DD]; vals[h] = x; ss += x * x; }
  float r = 1.0f / fmaxf(sqrtf(ss), 1e-12f);
  const int doff = (((d >> 3) ^ (s & 7)) << 3) + (d & 7);
  _Float16* op = kh + (size_t)b * HH * SS * DD + (size_t)s * DD + doff;
  #pragma unroll
  for (int h = 0; h < HH; ++h) op[(size_t)h * SS * DD] = (_Float16)(vals[h] * r);
}

// q -> f16, 8 elements/thread (plain layout; Q frags are a one-time load/block).
__global__ void cvt_f16(const float* __restrict__ x, _Float16* __restrict__ y) {
  size_t i = ((size_t)blockIdx.x * 256 + threadIdx.x) * 8;
  float4 a = *(const float4*)(x + i);
  float4 b = *(const float4*)(x + i + 4);
  f16x8 r = { (_Float16)a.x, (_Float16)a.y, (_Float16)a.z, (_Float16)a.w,
              (_Float16)b.x, (_Float16)b.y, (_Float16)b.z, (_Float16)b.w };
  *(f16x8*)(y + i) = r;
}

// v[b,h,s,d] -> V^T in CHUNK-MAJOR swizzled layout: per (bh), chunk c = key>>7
// is a 32 KB block [d=0..127][128 keys]; element (d,key) at
// c*16384 + d*128 + ((((key&127)>>3) ^ (d&7))<<3) + (key&7).
__global__ void vtrans_f16(const float* __restrict__ v, _Float16* __restrict__ vt) {
  __shared__ float tile[32][33];
  int bh = blockIdx.z;
  int d0 = blockIdx.x * 32, s0 = blockIdx.y * 32;
  const float* vp = v + (size_t)bh * SS * DD;
  _Float16* tp = vt + (size_t)bh * SS * DD;
  int tx = threadIdx.x, ty = threadIdx.y;       // block (32,8)
  #pragma unroll
  for (int i = ty; i < 32; i += 8)
    tile[i][tx] = vp[(size_t)(s0 + i) * DD + d0 + tx];
  __syncthreads();
  #pragma unroll
  for (int i = ty; i < 32; i += 8) {
    const int key = s0 + tx, dd = d0 + i;
    tp[(size_t)(key >> 7) * (DD * CHUNK) + (size_t)dd * CHUNK
       + ((((key & 127) >> 3) ^ (dd & 7)) << 3) + (key & 7)] = (_Float16)tile[tx][i];
  }
}

// ---------------- Fused attention (r8): producer/consumer + LDS staging -----
// 1024 thr, QBLK=16. Waves 0-7 ("mma"): QK^T/exp/softmax then PV. Waves 8-15
// ("staging"): global_load_lds K/V chunks into a 2x32KB dbuf with counted
// vmcnt + raw barriers; in phase 3 they also emit attn rows as contiguous
// 1KB wave-stores. All LDS fragment reads are XOR-swizzled (conflict-free).
__global__ __launch_bounds__(1024, 4) void attn_fused(
    const _Float16* __restrict__ qh, const _Float16* __restrict__ kh,
    const _Float16* __restrict__ vth, const int* __restrict__ mask,
    float* __restrict__ out, float* __restrict__ attn)
{
  __shared__ _Float16 sc[16 * SS];            // P, swizzled, 64 KB
  __shared__ _Float16 kv[2][CHUNK * DD];      // K/V chunk double buffer, 64 KB
  __shared__ float redsum[16][9];

  // XCD swizzle: wgid%8 = XCD; each XCD owns 4 heads, walks their q-tiles.
  const int wgid = blockIdx.x;                  // [0, 4096)
  const int xcd  = wgid & 7;
  const int idx  = wgid >> 3;                   // [0, 512)
  const int bh   = (xcd << 2) | (idx >> 7);     // 4 heads per XCD
  const int q0   = (idx & 127) * 16;
  const int b    = bh >> 4;

  const int lane = threadIdx.x & 63;
  const int w    = threadIdx.x >> 6;            // [0,16)
  const int lo16 = lane & 15;
  const int g    = lane >> 4;
  const bool is_mma = (w < 8);
  const int stid = (w - 8) * 64 + lane;         // staging tid [0,512)

  const size_t hoff = (size_t)bh * SS * DD;
  const _Float16* Q = qh  + hoff + (size_t)q0 * DD;
  const _Float16* K = kh  + hoff;               // swizzled [2048][128]
  const _Float16* V = vth + hoff;               // chunk-major swizzled
  const int* mrow = mask + b * SS;

  f16x8 qf[4];
  if (is_mma) {
    #pragma unroll
    for (int c = 0; c < 4; ++c)
      qf[c] = *(const f16x8*)(Q + lo16 * DD + c * 32 + g * 8);
  }

  // ---- Phase 1 prologue: stage K chunk 0 ----
  if (!is_mma) {
    #pragma unroll
    for (int j = 0; j < 4; ++j) {
      const int slot = stid + j * 512;          // 2048 slots x 16B = 32 KB
      load_lds16(K + slot * 8, &kv[0][slot * 8]);
    }
  }
  __syncthreads();                              // full drain: chunk 0 visible

  // ---- Phase 1: QK^T + exp, E held in AGPRs (mma waves) ----
  f32x4 acc[NCHUNK];
  float ssum = 0.f;
  #pragma unroll
  for (int c = 0; c < NCHUNK; ++c) {
    if (!is_mma) {
      if (c + 1 < NCHUNK) {
        #pragma unroll
        for (int j = 0; j < 4; ++j) {
          const int slot = stid + j * 512;
          load_lds16(K + (size_t)(c + 1) * (CHUNK * DD) + slot * 8,
                     &kv[(c + 1) & 1][slot * 8]);
        }
      }
      asm volatile("s_waitcnt vmcnt(0)" ::: "memory");
    } else {
      const _Float16* buf = kv[c & 1];
      const int row = w * 16 + lo16;            // key row within chunk
      f32x4 a = {0.f, 0.f, 0.f, 0.f};
      #pragma unroll
      for (int cc = 0; cc < 4; ++cc) {
        const int p = (cc * 4 + g) ^ (row & 7); // swizzled 16B slot
        f16x8 kf = *(const f16x8*)(buf + row * DD + p * 8);
        a = __builtin_amdgcn_mfma_f32_16x16x32_f16(kf, qf[cc], a, 0, 0, 0);
      }
      const int4 mv = *(const int4*)(mrow + c * CHUNK + w * 16 + g * 4);
      a[0] = mv.x ? __expf(a[0]) : 0.f;
      a[1] = mv.y ? __expf(a[1]) : 0.f;
      a[2] = mv.z ? __expf(a[2]) : 0.f;
      a[3] = mv.w ? __expf(a[3]) : 0.f;
      ssum += a[0] + a[1] + a[2] + a[3];
      acc[c] = a;
    }
    block_barrier();
  }

  // ---- Phase 2: denominator + P(f16) into swizzled LDS ----
  ssum += __shfl_xor(ssum, 16);
  ssum += __shfl_xor(ssum, 32);
  if (is_mma && lane < 16) redsum[lane][w] = ssum;
  __syncthreads();
  const float inv = 1.0f / (redsum[lo16][0] + redsum[lo16][1] + redsum[lo16][2] +
                            redsum[lo16][3] + redsum[lo16][4] + redsum[lo16][5] +
                            redsum[lo16][6] + redsum[lo16][7]);
  if (is_mma) {
    #pragma unroll
    for (int c = 0; c < NCHUNK; ++c) {
      const int kbase = c * CHUNK + w * 16 + g * 4;
      f16x4 ph = { (_Float16)(acc[c][0] * inv), (_Float16)(acc[c][1] * inv),
                   (_Float16)(acc[c][2] * inv), (_Float16)(acc[c][3] * inv) };
      *(f16x4*)(&sc[swz(lo16, kbase)]) = ph;
    }
  } else {
    // Phase 3 prologue: stage V chunk 0 (overlaps the sc writes)
    #pragma unroll
    for (int j = 0; j < 4; ++j) {
      const int slot = stid + j * 512;
      load_lds16(V + slot * 8, &kv[0][slot * 8]);
    }
  }
  __syncthreads();                              // drains sc writes + V chunk 0

  // ---- Phase 3: PV (mma waves) || attn stores + V staging (staging waves) --
  f32x4 oacc = {0.f, 0.f, 0.f, 0.f};
  #pragma unroll
  for (int c = 0; c < NCHUNK; ++c) {
    if (!is_mma) {
      if (c + 1 < NCHUNK) {
        #pragma unroll
        for (int j = 0; j < 4; ++j) {
          const int slot = stid + j * 512;
          load_lds16(V + (size_t)(c + 1) * (CHUNK * DD) + slot * 8,
                     &kv[(c + 1) & 1][slot * 8]);
        }
      }
      // attn row c: this wave emits plain floats [ (w-8)*256, +256 ) as one
      // contiguous 1KB wave-store; XOR lands on the LDS read address only.
      const int base = (w - 8) * 256 + lane * 4;
      const f16x4 p4 = *(const f16x4*)(&sc[c * SS + (base ^ ((c & 7) << 3))]);
      f32x4 pv = { (float)p4[0], (float)p4[1], (float)p4[2], (float)p4[3] };
      *(f32x4*)(attn + ((size_t)bh * SS + q0 + c) * SS + base) = pv;
      asm volatile("s_waitcnt vmcnt(1)" ::: "memory");   // drain loads, keep store
    } else {
      const _Float16* buf = kv[c & 1];
      const int dloc = w * 16 + lo16;           // V^T row (d) within chunk
      #pragma unroll
      for (int t = 0; t < 4; ++t) {
        const int p = (t * 4 + g) ^ (dloc & 7);
        f16x8 vf = *(const f16x8*)(buf + dloc * CHUNK + p * 8);
        f16x8 pf = *(const f16x8*)(&sc[swz(lo16, c * CHUNK + t * 32 + g * 8)]);
        oacc = __builtin_amdgcn_mfma_f32_16x16x32_f16(pf, vf, oacc, 0, 0, 0);
      }
    }
    block_barrier();
  }

  // ---- Epilogue: out stores (mma waves; wave w owns d-cols [w*16,+16)) ----
  if (is_mma) {
    float* O = out + hoff + (size_t)q0 * DD + w * 16;
    #pragma unroll
    for (int i = 0; i < 4; ++i) {
      const int qrow = g * 4 + i;               // C row = q, col = d
      O[(size_t)qrow * DD + lo16] = oacc[i];
    }
  }
}

extern "C" void kernel_launch(void* const* d_in, const int* in_sizes, int n_in,
                              void* d_out, int out_size, void* d_ws, size_t ws_size,
                              hipStream_t stream) {
  const float* q    = (const float*)d_in[0];
  const float* k    = (const float*)d_in[1];
  const float* v    = (const float*)d_in[2];
  const int*   mask = (const int*)d_in[3];

  const size_t N = (size_t)BB * HH * SS * DD;     // 8388608
  float* out  = (float*)d_out;
  float* attn = out + N;                          // outputs concatenated (out, attn)

  // scratch: 3 f16 tensors = 48 MB
  _Float16* qh  = (_Float16*)d_ws;
  _Float16* kh  = qh + N;
  _Float16* vth = kh + N;

  cvt_f16  <<<N / 8 / 256, 256, 0, stream>>>(q, qh);
  knorm_f16<<<(BB * SS * DD) / 256, 256, 0, stream>>>(k, kh);
  vtrans_f16<<<dim3(DD / 32, SS / 32, BB * HH), dim3(32, 8), 0, stream>>>(v, vth);

  attn_fused<<<4096, 1024, 0, stream>>>(qh, kh, vth, mask, out, attn);
}

// Round 9
// 424.081 us; speedup vs baseline: 2.2253x; 1.0669x over previous
//
#include <hip/hip_runtime.h>
#include <hip/hip_fp16.h>

// Sizes fixed by the reference.
#define BB 2
#define HH 16
#define SS 2048
#define DD 128
#define CHUNK 128          // keys per staged K/V chunk (32 KB f16 each)
#define NCHUNK 16          // SS / CHUNK
#define CSHIFT 14.0f       // E' = exp(s - 14): row max s ~ 20 -> e^6 = 403 (f16-safe);
                           // shift cancels in p = E'/sum(E') and in out = (E'V)/sum(E')

typedef __attribute__((ext_vector_type(8))) _Float16 f16x8;
typedef __attribute__((ext_vector_type(4))) _Float16 f16x4;
typedef __attribute__((ext_vector_type(4))) float    f32x4;

__device__ __forceinline__ void load_lds16(const void* g, void* l) {
  __builtin_amdgcn_global_load_lds(
      (const __attribute__((address_space(1))) void*)g,
      (__attribute__((address_space(3))) void*)l, 16, 0, 0);
}

__device__ __forceinline__ void block_barrier() {
  asm volatile("" ::: "memory");
  __builtin_amdgcn_s_barrier();
  asm volatile("" ::: "memory");
}

// k_norm = k / max(||k||_2 over HEAD axis, eps), cast to f16, stored in a
// PRE-SWIZZLED row layout: element (s,d) at s*128 + (((d>>3)^(s&7))<<3)+(d&7).
// Linear global_load_lds then yields an LDS image with conflict-free
// XOR-swizzled fragment reads.
__global__ void knorm_f16(const float* __restrict__ k, _Float16* __restrict__ kh) {
  int t = blockIdx.x * 256 + threadIdx.x;      // [0, B*S*D)
  int d = t & (DD - 1);
  int s = (t >> 7) & (SS - 1);
  int b = t >> 18;                              // S*D = 2^18
  const float* kp = k + (size_t)b * HH * SS * DD + (size_t)s * DD + d;
  float vals[HH];
  float ss = 0.f;
  #pragma unroll
  for (int h = 0; h < HH; ++h) { float x = kp[(size_t)h * SS * DD]; vals[h] = x; ss += x * x; }
  float r = 1.0f / fmaxf(sqrtf(ss), 1e-12f);
  const int doff = (((d >> 3) ^ (s & 7)) << 3) + (d & 7);
  _Float16* op = kh + (size_t)b * HH * SS * DD + (size_t)s * DD + doff;
  #pragma unroll
  for (int h = 0; h < HH; ++h) op[(size_t)h * SS * DD] = (_Float16)(vals[h] * r);
}

// q -> f16, 8 elements/thread (plain layout).
__global__ void cvt_f16(const float* __restrict__ x, _Float16* __restrict__ y) {
  size_t i = ((size_t)blockIdx.x * 256 + threadIdx.x) * 8;
  float4 a = *(const float4*)(x + i);
  float4 b = *(const float4*)(x + i + 4);
  f16x8 r = { (_Float16)a.x, (_Float16)a.y, (_Float16)a.z, (_Float16)a.w,
              (_Float16)b.x, (_Float16)b.y, (_Float16)b.z, (_Float16)b.w };
  *(f16x8*)(y + i) = r;
}

// v[b,h,s,d] -> V^T in CHUNK-MAJOR swizzled layout: chunk c = key>>7 is a
// 32 KB block [d][128 keys]; element (d,key) at
// c*16384 + d*128 + ((((key&127)>>3) ^ (d&7))<<3) + (key&7).
__global__ void vtrans_f16(const float* __restrict__ v, _Float16* __restrict__ vt) {
  __shared__ float tile[32][33];
  int bh = blockIdx.z;
  int d0 = blockIdx.x * 32, s0 = blockIdx.y * 32;
  const float* vp = v + (size_t)bh * SS * DD;
  _Float16* tp = vt + (size_t)bh * SS * DD;
  int tx = threadIdx.x, ty = threadIdx.y;       // block (32,8)
  #pragma unroll
  for (int i = ty; i < 32; i += 8)
    tile[i][tx] = vp[(size_t)(s0 + i) * DD + d0 + tx];
  __syncthreads();
  #pragma unroll
  for (int i = ty; i < 32; i += 8) {
    const int key = s0 + tx, dd = d0 + i;
    tp[(size_t)(key >> 7) * (DD * CHUNK) + (size_t)dd * CHUNK
       + ((((key & 127) >> 3) ^ (dd & 7)) << 3) + (key & 7)] = (_Float16)tile[tx][i];
  }
}

// ---------------- Fused attention (r9): single-pass QK^T+PV per chunk -------
// 1024 thr. Waves 0-7 (mma): per chunk c do QK^T -> E'=exp(s-14) (kept packed
// f16 in acc_h[c], 32 regs total) -> ptile to 4KB pbuf -> barrier -> PV on
// UNNORMALIZED E' (inv applied to oacc at the end; valid since inv is per-q).
// Waves 8-15 (staging): global_load_lds K+V chunk c+1 (64 KB) issued at phase
// start, vmcnt(0) only before the phase-end barrier. 16 phases total (r8: 32),
// no 64KB sc buffer, no separate softmax round. LDS 136.6 KB -> 1 block/CU.
__global__ __launch_bounds__(1024, 4) void attn_fused(
    const _Float16* __restrict__ qh, const _Float16* __restrict__ kh,
    const _Float16* __restrict__ vth, const int* __restrict__ mask,
    float* __restrict__ out, float* __restrict__ attn)
{
  __shared__ _Float16 kbuf[2][CHUNK * DD];   // 64 KB
  __shared__ _Float16 vbuf[2][DD * CHUNK];   // 64 KB
  __shared__ _Float16 pbuf[2][16 * CHUNK];   // 8 KB
  __shared__ float redsum[16][9];

  // XCD swizzle: wgid%8 = XCD; each XCD owns 4 heads, walks their q-tiles.
  const int wgid = blockIdx.x;                  // [0, 4096)
  const int xcd  = wgid & 7;
  const int idx  = wgid >> 3;                   // [0, 512)
  const int bh   = (xcd << 2) | (idx >> 7);     // 4 heads per XCD
  const int q0   = (idx & 127) * 16;
  const int b    = bh >> 4;

  const int lane = threadIdx.x & 63;
  const int w    = threadIdx.x >> 6;            // [0,16)
  const int lo16 = lane & 15;
  const int g    = lane >> 4;
  const bool is_mma = (w < 8);
  const int stid = (w - 8) * 64 + lane;         // staging tid [0,512)

  const size_t hoff = (size_t)bh * SS * DD;
  const _Float16* Q = qh  + hoff + (size_t)q0 * DD;
  const _Float16* K = kh  + hoff;               // pre-swizzled [2048][128]
  const _Float16* V = vth + hoff;               // chunk-major pre-swizzled
  const int* mrow = mask + b * SS;

  f16x8 qf[4];
  if (is_mma) {
    #pragma unroll
    for (int c = 0; c < 4; ++c)
      qf[c] = *(const f16x8*)(Q + lo16 * DD + c * 32 + g * 8);
  }

  // ---- Prologue: stage K+V chunk 0 ----
  if (!is_mma) {
    #pragma unroll
    for (int j = 0; j < 4; ++j) {
      const int slot = stid + j * 512;          // 2048 slots x 16B = 32 KB
      load_lds16(K + slot * 8, &kbuf[0][slot * 8]);
    }
    #pragma unroll
    for (int j = 0; j < 4; ++j) {
      const int slot = stid + j * 512;
      load_lds16(V + slot * 8, &vbuf[0][slot * 8]);
    }
  }
  __syncthreads();                              // chunk 0 resident

  f16x4 acc_h[NCHUNK];                          // E' per chunk (q=lo16, 4 keys)
  f32x4 oacc = {0.f, 0.f, 0.f, 0.f};
  float ssum = 0.f;

  #pragma unroll
  for (int c = 0; c < NCHUNK; ++c) {
    if (!is_mma) {
      // ---- staging: issue K+V chunk c+1 (8 x 1KB wave-loads) ----
      if (c + 1 < NCHUNK) {
        #pragma unroll
        for (int j = 0; j < 4; ++j) {
          const int slot = stid + j * 512;
          load_lds16(K + (size_t)(c + 1) * (CHUNK * DD) + slot * 8,
                     &kbuf[(c + 1) & 1][slot * 8]);
        }
        #pragma unroll
        for (int j = 0; j < 4; ++j) {
          const int slot = stid + j * 512;
          load_lds16(V + (size_t)(c + 1) * (CHUNK * DD) + slot * 8,
                     &vbuf[(c + 1) & 1][slot * 8]);
        }
      }
    } else {
      // ---- QK^T chunk c: wave owns keys [c*128 + w*16, +16) ----
      const _Float16* kb = kbuf[c & 1];
      const int row = w * 16 + lo16;
      f32x4 a = {0.f, 0.f, 0.f, 0.f};
      __builtin_amdgcn_s_setprio(1);
      #pragma unroll
      for (int cc = 0; cc < 4; ++cc) {
        const int p = (cc * 4 + g) ^ (row & 7); // swizzled 16B slot
        f16x8 kf = *(const f16x8*)(kb + row * DD + p * 8);
        a = __builtin_amdgcn_mfma_f32_16x16x32_f16(kf, qf[cc], a, 0, 0, 0);
      }
      __builtin_amdgcn_s_setprio(0);
      // D[key][q]: lane holds q=lo16, keys w*16+g*4+i
      const int4 mv = *(const int4*)(mrow + c * CHUNK + w * 16 + g * 4);
      const float e0 = mv.x ? __expf(a[0] - CSHIFT) : 0.f;
      const float e1 = mv.y ? __expf(a[1] - CSHIFT) : 0.f;
      const float e2 = mv.z ? __expf(a[2] - CSHIFT) : 0.f;
      const float e3 = mv.w ? __expf(a[3] - CSHIFT) : 0.f;
      ssum += e0 + e1 + e2 + e3;
      f16x4 eh = { (_Float16)e0, (_Float16)e1, (_Float16)e2, (_Float16)e3 };
      acc_h[c] = eh;
      // ptile[q=lo16][keys w*16+g*4..+3], XOR-swizzled by q&7 (16B groups)
      const int kk = w * 16 + g * 4;
      const int paddr = lo16 * CHUNK + ((kk & ~7) ^ ((lo16 & 7) << 3)) + (kk & 7);
      *(f16x4*)(&pbuf[c & 1][paddr]) = eh;
      asm volatile("s_waitcnt lgkmcnt(0)" ::: "memory");  // ptile visible pre-barrier
    }
    block_barrier();   // barrier 1: ptile(c) visible; KV[c] resident since prev phase

    if (is_mma) {
      // ---- PV chunk c on unnormalized E': wave owns d-cols [w*16,+16) ----
      const _Float16* vb = vbuf[c & 1];
      const _Float16* pb = pbuf[c & 1];
      const int dloc = w * 16 + lo16;
      __builtin_amdgcn_s_setprio(1);
      #pragma unroll
      for (int t = 0; t < 4; ++t) {
        const int pv_ = (t * 4 + g) ^ (dloc & 7);
        f16x8 vf = *(const f16x8*)(vb + dloc * CHUNK + pv_ * 8);
        const int pk = t * 32 + g * 8;
        f16x8 pf = *(const f16x8*)(pb + lo16 * CHUNK + (pk ^ ((lo16 & 7) << 3)));
        oacc = __builtin_amdgcn_mfma_f32_16x16x32_f16(pf, vf, oacc, 0, 0, 0);
      }
      __builtin_amdgcn_s_setprio(0);
    } else {
      asm volatile("s_waitcnt vmcnt(0)" ::: "memory");    // KV[c+1] landed
    }
    block_barrier();   // barrier 2: KV[c+1] resident; PV(c) done before buf reuse
  }

  // ---- Epilogue: denominator, attn from regs, out from oacc ----
  ssum += __shfl_xor(ssum, 16);
  ssum += __shfl_xor(ssum, 32);
  if (is_mma && lane < 16) redsum[lane][w] = ssum;
  __syncthreads();

  if (is_mma) {
    float denom = 0.f;
    #pragma unroll
    for (int j = 0; j < 8; ++j) denom += redsum[lo16][j];
    const float inv = 1.0f / denom;

    // attn[q0+lo16][c*128 + w*16 + g*4 ..+3] = E' * inv  (f32, from registers)
    float* arow = attn + ((size_t)bh * SS + q0 + lo16) * SS + w * 16 + g * 4;
    #pragma unroll
    for (int c = 0; c < NCHUNK; ++c) {
      f32x4 pst = { (float)acc_h[c][0] * inv, (float)acc_h[c][1] * inv,
                    (float)acc_h[c][2] * inv, (float)acc_h[c][3] * inv };
      *(f32x4*)(arow + c * CHUNK) = pst;
    }

    // out: PV C layout row=q=g*4+i, col=d=lo16; scale by that q's inv
    float* O = out + hoff + (size_t)q0 * DD + w * 16;
    #pragma unroll
    for (int i = 0; i < 4; ++i) {
      const int qr = g * 4 + i;
      float dq = 0.f;
      #pragma unroll
      for (int j = 0; j < 8; ++j) dq += redsum[qr][j];
      O[(size_t)qr * DD + lo16] = oacc[i] / dq;
    }
  }
}

extern "C" void kernel_launch(void* const* d_in, const int* in_sizes, int n_in,
                              void* d_out, int out_size, void* d_ws, size_t ws_size,
                              hipStream_t stream) {
  const float* q    = (const float*)d_in[0];
  const float* k    = (const float*)d_in[1];
  const float* v    = (const float*)d_in[2];
  const int*   mask = (const int*)d_in[3];

  const size_t N = (size_t)BB * HH * SS * DD;     // 8388608
  float* out  = (float*)d_out;
  float* attn = out + N;                          // outputs concatenated (out, attn)

  // scratch: 3 f16 tensors = 48 MB
  _Float16* qh  = (_Float16*)d_ws;
  _Float16* kh  = qh + N;
  _Float16* vth = kh + N;

  cvt_f16  <<<N / 8 / 256, 256, 0, stream>>>(q, qh);
  knorm_f16<<<(BB * SS * DD) / 256, 256, 0, stream>>>(k, kh);
  vtrans_f16<<<dim3(DD / 32, SS / 32, BB * HH), dim3(32, 8), 0, stream>>>(v, vth);

  attn_fused<<<4096, 1024, 0, stream>>>(qh, kh, vth, mask, out, attn);
}

// Round 10
// 364.636 us; speedup vs baseline: 2.5880x; 1.1630x over previous
//
#include <hip/hip_runtime.h>
#include <hip/hip_fp16.h>

// Sizes fixed by the reference.
#define BB 2
#define HH 16
#define SS 2048
#define DD 128
#define CHUNK 128          // keys per staged K/V chunk (32 KB f16 each)
#define NCHUNK 16          // SS / CHUNK
#define QBLK 32            // q-rows per block
#define CSHIFT 14.0f       // E' = exp(s-14); |s| <= ||q|| ~ 14 -> E' f16-safe; shift cancels

typedef __attribute__((ext_vector_type(8))) _Float16 f16x8;
typedef __attribute__((ext_vector_type(4))) _Float16 f16x4;
typedef __attribute__((ext_vector_type(4))) float    f32x4;

__device__ __forceinline__ void load_lds16(const void* g, void* l) {
  __builtin_amdgcn_global_load_lds(
      (const __attribute__((address_space(1))) void*)g,
      (__attribute__((address_space(3))) void*)l, 16, 0, 0);
}

__device__ __forceinline__ void block_barrier() {
  asm volatile("" ::: "memory");
  __builtin_amdgcn_s_barrier();
  asm volatile("" ::: "memory");
}

// k_norm = k / max(||k||_2 over HEAD axis, eps), f16, PRE-SWIZZLED row layout:
// (s,d) at s*128 + (((d>>3)^(s&7))<<3) + (d&7). Linear global_load_lds then
// gives conflict-free XOR-swizzled fragment reads in LDS.
__global__ void knorm_f16(const float* __restrict__ k, _Float16* __restrict__ kh) {
  int t = blockIdx.x * 256 + threadIdx.x;      // [0, B*S*D)
  int d = t & (DD - 1);
  int s = (t >> 7) & (SS - 1);
  int b = t >> 18;                              // S*D = 2^18
  const float* kp = k + (size_t)b * HH * SS * DD + (size_t)s * DD + d;
  float vals[HH];
  float ss = 0.f;
  #pragma unroll
  for (int h = 0; h < HH; ++h) { float x = kp[(size_t)h * SS * DD]; vals[h] = x; ss += x * x; }
  float r = 1.0f / fmaxf(sqrtf(ss), 1e-12f);
  const int doff = (((d >> 3) ^ (s & 7)) << 3) + (d & 7);
  _Float16* op = kh + (size_t)b * HH * SS * DD + (size_t)s * DD + doff;
  #pragma unroll
  for (int h = 0; h < HH; ++h) op[(size_t)h * SS * DD] = (_Float16)(vals[h] * r);
}

// q -> f16, 8 elements/thread (plain layout).
__global__ void cvt_f16(const float* __restrict__ x, _Float16* __restrict__ y) {
  size_t i = ((size_t)blockIdx.x * 256 + threadIdx.x) * 8;
  float4 a = *(const float4*)(x + i);
  float4 b = *(const float4*)(x + i + 4);
  f16x8 r = { (_Float16)a.x, (_Float16)a.y, (_Float16)a.z, (_Float16)a.w,
              (_Float16)b.x, (_Float16)b.y, (_Float16)b.z, (_Float16)b.w };
  *(f16x8*)(y + i) = r;
}

// v[b,h,s,d] -> V^T chunk-major swizzled: chunk c = key>>7 is a 32 KB block;
// element (d,key) at c*16384 + d*128 + ((((key&127)>>3)^(d&7))<<3) + (key&7).
__global__ void vtrans_f16(const float* __restrict__ v, _Float16* __restrict__ vt) {
  __shared__ float tile[32][33];
  int bh = blockIdx.z;
  int d0 = blockIdx.x * 32, s0 = blockIdx.y * 32;
  const float* vp = v + (size_t)bh * SS * DD;
  _Float16* tp = vt + (size_t)bh * SS * DD;
  int tx = threadIdx.x, ty = threadIdx.y;       // block (32,8)
  #pragma unroll
  for (int i = ty; i < 32; i += 8)
    tile[i][tx] = vp[(size_t)(s0 + i) * DD + d0 + tx];
  __syncthreads();
  #pragma unroll
  for (int i = ty; i < 32; i += 8) {
    const int key = s0 + tx, dd = d0 + i;
    tp[(size_t)(key >> 7) * (DD * CHUNK) + (size_t)dd * CHUNK
       + ((((key & 127) >> 3) ^ (dd & 7)) << 3) + (key & 7)] = (_Float16)tile[tx][i];
  }
}

// ---------------- Fused attention (r10): all-wave 2-phase pipeline ----------
// QBLK=32, 1024 thr, 16 waves; wave w = (qhf = w>>3) q-half x (sub = w&7).
// Per chunk c: [issue K+V chunk c+1 via global_load_lds] ; QK^T tile
// (keys sub*16.. x q-half) -> E'=exp(s-14) kept packed f16 + pbuf ;
// lgkmcnt(0) ; barrier ; PV tile (d-cols sub*16.. x q-half) on unnormalized
// E' ; vmcnt(0) ; barrier. Staging latency hides under the SAME wave's
// MFMA work (r9's split left 8 waves idle-spinning at vmcnt).
// Regs ~90 < 128 cap at (1024,4): no spill. LDS 137 KB -> 1 block/CU.
__global__ __launch_bounds__(1024, 4) void attn_fused(
    const _Float16* __restrict__ qh, const _Float16* __restrict__ kh,
    const _Float16* __restrict__ vth, const int* __restrict__ mask,
    float* __restrict__ out, float* __restrict__ attn)
{
  __shared__ _Float16 kbuf[2][CHUNK * DD];   // 64 KB
  __shared__ _Float16 vbuf[2][DD * CHUNK];   // 64 KB
  __shared__ _Float16 pbuf[QBLK * CHUNK];    // 8 KB (single: guarded by the 2 barriers)
  __shared__ float redsum[2][16][9];

  // XCD swizzle: wgid%8 = XCD; each XCD owns 4 heads, walks their q-tiles.
  const int wgid = blockIdx.x;                  // [0, 2048)
  const int xcd  = wgid & 7;
  const int idx  = wgid >> 3;                   // [0, 256)
  const int bh   = (xcd << 2) | (idx >> 6);     // 4 heads per XCD
  const int q0   = (idx & 63) * QBLK;
  const int b    = bh >> 4;

  const int tid  = threadIdx.x;
  const int lane = tid & 63;
  const int w    = tid >> 6;                    // [0,16)
  const int lo16 = lane & 15;
  const int g    = lane >> 4;
  const int qhf  = w >> 3;                      // q-half
  const int sub  = w & 7;                       // key-group (QK^T) / d-group (PV)

  const size_t hoff = (size_t)bh * SS * DD;
  const _Float16* Q = qh  + hoff + (size_t)q0 * DD;
  const _Float16* K = kh  + hoff;               // pre-swizzled [2048][128]
  const _Float16* V = vth + hoff;               // chunk-major pre-swizzled
  const int* mrow = mask + b * SS;

  const int prow = qhf * 16 + lo16;             // this lane's q row (QK^T col / PV A-row)

  f16x8 qf[4];
  #pragma unroll
  for (int c = 0; c < 4; ++c)
    qf[c] = *(const f16x8*)(Q + (size_t)prow * DD + c * 32 + g * 8);

  // ---- Prologue: stage K+V chunk 0 (all 1024 threads, 2+2 x 16B each) ----
  #pragma unroll
  for (int j = 0; j < 2; ++j) {
    const int slot = tid + j * 1024;            // 2048 slots x 16 B = 32 KB
    load_lds16(K + slot * 8, &kbuf[0][slot * 8]);
    load_lds16(V + slot * 8, &vbuf[0][slot * 8]);
  }
  __syncthreads();                              // chunk 0 resident

  f16x4 acc_h[NCHUNK];                          // E' (4 keys/lane/chunk), 32 regs
  f32x4 oacc = {0.f, 0.f, 0.f, 0.f};
  float ssum = 0.f;

  #pragma unroll
  for (int c = 0; c < NCHUNK; ++c) {
    const _Float16* kb = kbuf[c & 1];
    const _Float16* vb = vbuf[c & 1];

    // ---- issue staging for chunk c+1 (latency hides under QK^T+PV) ----
    if (c + 1 < NCHUNK) {
      #pragma unroll
      for (int j = 0; j < 2; ++j) {
        const int slot = tid + j * 1024;
        load_lds16(K + (size_t)(c + 1) * (CHUNK * DD) + slot * 8,
                   &kbuf[(c + 1) & 1][slot * 8]);
        load_lds16(V + (size_t)(c + 1) * (CHUNK * DD) + slot * 8,
                   &vbuf[(c + 1) & 1][slot * 8]);
      }
    }

    // ---- QK^T: keys [sub*16,+16) x q-half qhf ----
    {
      const int row = sub * 16 + lo16;          // key row within chunk
      f32x4 a = {0.f, 0.f, 0.f, 0.f};
      #pragma unroll
      for (int cc = 0; cc < 4; ++cc) {
        const int p = (cc * 4 + g) ^ (row & 7); // swizzled 16B slot
        f16x8 kf = *(const f16x8*)(kb + row * DD + p * 8);
        a = __builtin_amdgcn_mfma_f32_16x16x32_f16(kf, qf[cc], a, 0, 0, 0);
      }
      // D[key][q]: lane holds q=prow, keys sub*16 + g*4 + i
      const int4 mv = *(const int4*)(mrow + c * CHUNK + sub * 16 + g * 4);
      const float e0 = mv.x ? __expf(a[0] - CSHIFT) : 0.f;
      const float e1 = mv.y ? __expf(a[1] - CSHIFT) : 0.f;
      const float e2 = mv.z ? __expf(a[2] - CSHIFT) : 0.f;
      const float e3 = mv.w ? __expf(a[3] - CSHIFT) : 0.f;
      ssum += e0 + e1 + e2 + e3;
      f16x4 eh = { (_Float16)e0, (_Float16)e1, (_Float16)e2, (_Float16)e3 };
      acc_h[c] = eh;
      const int col = sub * 16 + g * 4;         // key col in pbuf row
      *(f16x4*)(&pbuf[prow * CHUNK + (((col >> 3) ^ (prow & 7)) << 3) + (col & 7)]) = eh;
    }
    asm volatile("s_waitcnt lgkmcnt(0)" ::: "memory");   // pbuf visible
    block_barrier();                             // barrier 1

    // ---- PV on unnormalized E': d-cols [sub*16,+16) x q-half qhf ----
    {
      const int dloc = sub * 16 + lo16;
      #pragma unroll
      for (int t = 0; t < 4; ++t) {
        const int pv_ = (t * 4 + g) ^ (dloc & 7);
        f16x8 vf = *(const f16x8*)(vb + dloc * CHUNK + pv_ * 8);
        f16x8 pf = *(const f16x8*)(&pbuf[prow * CHUNK + ((t * 32 + g * 8) ^ ((prow & 7) << 3))]);
        oacc = __builtin_amdgcn_mfma_f32_16x16x32_f16(pf, vf, oacc, 0, 0, 0);
      }
    }
    asm volatile("s_waitcnt vmcnt(0)" ::: "memory");     // chunk c+1 landed
    block_barrier();                             // barrier 2
  }

  // ---- Epilogue: denominators, attn from regs, out from oacc ----
  ssum += __shfl_xor(ssum, 16);                 // reduce over g groups
  ssum += __shfl_xor(ssum, 32);                 // -> sum over this wave's 16 keys
  if (lane < 16) redsum[qhf][lane][sub] = ssum;
  __syncthreads();

  float denom = 0.f;
  #pragma unroll
  for (int j = 0; j < 8; ++j) denom += redsum[qhf][lo16][j];
  const float inv = 1.0f / denom;

  // attn[q0+prow][c*128 + sub*16 + g*4 ..+3] = E' * inv (f32, from registers)
  float* arow = attn + ((size_t)bh * SS + q0 + prow) * SS + sub * 16 + g * 4;
  #pragma unroll
  for (int c = 0; c < NCHUNK; ++c) {
    f32x4 pst = { (float)acc_h[c][0] * inv, (float)acc_h[c][1] * inv,
                  (float)acc_h[c][2] * inv, (float)acc_h[c][3] * inv };
    *(f32x4*)(arow + c * CHUNK) = pst;
  }

  // out: C row = q = qhf*16 + g*4 + i, col = d = sub*16 + lo16
  float* O = out + hoff + (size_t)q0 * DD + sub * 16;
  #pragma unroll
  for (int i = 0; i < 4; ++i) {
    const int qr = g * 4 + i;
    float dq = 0.f;
    #pragma unroll
    for (int j = 0; j < 8; ++j) dq += redsum[qhf][qr][j];
    O[(size_t)(qhf * 16 + qr) * DD + lo16] = oacc[i] / dq;
  }
}

extern "C" void kernel_launch(void* const* d_in, const int* in_sizes, int n_in,
                              void* d_out, int out_size, void* d_ws, size_t ws_size,
                              hipStream_t stream) {
  const float* q    = (const float*)d_in[0];
  const float* k    = (const float*)d_in[1];
  const float* v    = (const float*)d_in[2];
  const int*   mask = (const int*)d_in[3];

  const size_t N = (size_t)BB * HH * SS * DD;     // 8388608
  float* out  = (float*)d_out;
  float* attn = out + N;                          // outputs concatenated (out, attn)

  // scratch: 3 f16 tensors = 48 MB
  _Float16* qh  = (_Float16*)d_ws;
  _Float16* kh  = qh + N;
  _Float16* vth = kh + N;

  cvt_f16  <<<N / 8 / 256, 256, 0, stream>>>(q, qh);
  knorm_f16<<<(BB * SS * DD) / 256, 256, 0, stream>>>(k, kh);
  vtrans_f16<<<dim3(DD / 32, SS / 32, BB * HH), dim3(32, 8), 0, stream>>>(v, vth);

  // 64 q-tiles x 32 heads, XCD-swizzled inside the kernel
  attn_fused<<<2048, 1024, 0, stream>>>(qh, kh, vth, mask, out, attn);
}

// Round 11
// 313.755 us; speedup vs baseline: 3.0077x; 1.1622x over previous
//
#include <hip/hip_runtime.h>
#include <hip/hip_fp16.h>

// Sizes fixed by the reference.
#define BB 2
#define HH 16
#define SS 2048
#define DD 128
#define CHUNK 64           // keys per staged K/V chunk (16 KB f16 each)
#define NCHUNK 32          // SS / CHUNK
#define QBLK 32            // q-rows per block
#define CSHIFT 14.0f       // E' = exp(s-14); |s| <= ||q|| ~ 14 -> E' f16-safe; shift cancels

typedef __attribute__((ext_vector_type(8))) _Float16 f16x8;
typedef __attribute__((ext_vector_type(4))) _Float16 f16x4;
typedef __attribute__((ext_vector_type(4))) float    f32x4;

__device__ __forceinline__ void load_lds16(const void* g, void* l) {
  __builtin_amdgcn_global_load_lds(
      (const __attribute__((address_space(1))) void*)g,
      (__attribute__((address_space(3))) void*)l, 16, 0, 0);
}

__device__ __forceinline__ void block_barrier() {
  asm volatile("" ::: "memory");
  __builtin_amdgcn_s_barrier();
  asm volatile("" ::: "memory");
}

// k_norm = k / max(||k||_2 over HEAD axis, eps), f16, PRE-SWIZZLED row layout:
// (s,d) at s*128 + (((d>>3)^(s&7))<<3) + (d&7). Linear global_load_lds then
// gives conflict-free XOR-swizzled fragment reads in LDS.
__global__ void knorm_f16(const float* __restrict__ k, _Float16* __restrict__ kh) {
  int t = blockIdx.x * 256 + threadIdx.x;      // [0, B*S*D)
  int d = t & (DD - 1);
  int s = (t >> 7) & (SS - 1);
  int b = t >> 18;                              // S*D = 2^18
  const float* kp = k + (size_t)b * HH * SS * DD + (size_t)s * DD + d;
  float vals[HH];
  float ss = 0.f;
  #pragma unroll
  for (int h = 0; h < HH; ++h) { float x = kp[(size_t)h * SS * DD]; vals[h] = x; ss += x * x; }
  float r = 1.0f / fmaxf(sqrtf(ss), 1e-12f);
  const int doff = (((d >> 3) ^ (s & 7)) << 3) + (d & 7);
  _Float16* op = kh + (size_t)b * HH * SS * DD + (size_t)s * DD + doff;
  #pragma unroll
  for (int h = 0; h < HH; ++h) op[(size_t)h * SS * DD] = (_Float16)(vals[h] * r);
}

// q -> f16, 8 elements/thread (plain layout).
__global__ void cvt_f16(const float* __restrict__ x, _Float16* __restrict__ y) {
  size_t i = ((size_t)blockIdx.x * 256 + threadIdx.x) * 8;
  float4 a = *(const float4*)(x + i);
  float4 b = *(const float4*)(x + i + 4);
  f16x8 r = { (_Float16)a.x, (_Float16)a.y, (_Float16)a.z, (_Float16)a.w,
              (_Float16)b.x, (_Float16)b.y, (_Float16)b.z, (_Float16)b.w };
  *(f16x8*)(y + i) = r;
}

// v[b,h,s,d] -> V^T in 64-key chunk-major swizzled layout: chunk c = key>>6 is
// a 16 KB block [d][64 keys]; element (d,key) at
// c*8192 + d*64 + ((((key&63)>>3) ^ (d&7))<<3) + (key&7).
__global__ void vtrans_f16(const float* __restrict__ v, _Float16* __restrict__ vt) {
  __shared__ float tile[32][33];
  int bh = blockIdx.z;
  int d0 = blockIdx.x * 32, s0 = blockIdx.y * 32;
  const float* vp = v + (size_t)bh * SS * DD;
  _Float16* tp = vt + (size_t)bh * SS * DD;
  int tx = threadIdx.x, ty = threadIdx.y;       // block (32,8)
  #pragma unroll
  for (int i = ty; i < 32; i += 8)
    tile[i][tx] = vp[(size_t)(s0 + i) * DD + d0 + tx];
  __syncthreads();
  #pragma unroll
  for (int i = ty; i < 32; i += 8) {
    const int key = s0 + tx, dd = d0 + i;
    tp[(size_t)(key >> 6) * (DD * CHUNK) + (size_t)dd * CHUNK
       + ((((key & 63) >> 3) ^ (dd & 7)) << 3) + (key & 7)] = (_Float16)tile[tx][i];
  }
}

// ---------------- Fused attention (r11): 2 blocks/CU overlap ----------------
// 512 thr (8 waves), QBLK=32, CHUNK=64. Wave w = (qhf = w>>2) q-half x
// (sub = w&3). Per chunk: issue K+V c+1 staging; QK^T tile (keys sub*16..)
// -> E'=exp(s-14) packed f16 + pbuf; lgkmcnt(0); barrier; PV (d-cols sub*32..,
// 2 tiles x 2 k-slices) on unnormalized E'; vmcnt(0); barrier.
// LDS ~70 KB and 128-reg cap -> TWO blocks co-resident per CU: one block's
// staging drain overlaps the other's MFMA phase (r10's 137 KB = 1 block/CU
// left every vmcnt/barrier stall exposed).
__global__ __launch_bounds__(512, 4) void attn_fused(
    const _Float16* __restrict__ qh, const _Float16* __restrict__ kh,
    const _Float16* __restrict__ vth, const int* __restrict__ mask,
    float* __restrict__ out, float* __restrict__ attn)
{
  __shared__ _Float16 kbuf[2][CHUNK * DD];   // 32 KB
  __shared__ _Float16 vbuf[2][DD * CHUNK];   // 32 KB
  __shared__ _Float16 pbuf[QBLK * CHUNK];    // 4 KB (guarded by the 2 barriers)
  __shared__ float redsum[2][16][5];

  // XCD swizzle: wgid%8 = XCD; each XCD owns 4 heads, walks their q-tiles.
  const int wgid = blockIdx.x;                  // [0, 2048)
  const int xcd  = wgid & 7;
  const int idx  = wgid >> 3;                   // [0, 256)
  const int bh   = (xcd << 2) | (idx >> 6);     // 4 heads per XCD
  const int q0   = (idx & 63) * QBLK;
  const int b    = bh >> 4;

  const int tid  = threadIdx.x;
  const int lane = tid & 63;
  const int w    = tid >> 6;                    // [0,8)
  const int lo16 = lane & 15;
  const int g    = lane >> 4;
  const int qhf  = w >> 2;                      // q-half
  const int sub  = w & 3;                       // key-group (QK^T) / d-group (PV)

  const size_t hoff = (size_t)bh * SS * DD;
  const _Float16* Q = qh  + hoff + (size_t)q0 * DD;
  const _Float16* K = kh  + hoff;               // pre-swizzled [2048][128]
  const _Float16* V = vth + hoff;               // 64-key chunk-major swizzled
  const int* mrow = mask + b * SS;

  const int prow = qhf * 16 + lo16;             // this lane's q row

  f16x8 qf[4];
  #pragma unroll
  for (int c = 0; c < 4; ++c)
    qf[c] = *(const f16x8*)(Q + (size_t)prow * DD + c * 32 + g * 8);

  // ---- Prologue: stage K+V chunk 0 (512 thr x (2K+2V) x 16 B) ----
  #pragma unroll
  for (int j = 0; j < 2; ++j) {
    const int slot = tid + j * 512;             // 1024 slots x 16 B = 16 KB
    load_lds16(K + slot * 8, &kbuf[0][slot * 8]);
    load_lds16(V + slot * 8, &vbuf[0][slot * 8]);
  }
  __syncthreads();                              // chunk 0 resident

  f16x4 acc_h[NCHUNK];                          // E' (4 keys/lane/chunk), 64 regs
  f32x4 oacc[2] = { {0,0,0,0}, {0,0,0,0} };
  float ssum = 0.f;

  #pragma unroll
  for (int c = 0; c < NCHUNK; ++c) {
    const _Float16* kb = kbuf[c & 1];
    const _Float16* vb = vbuf[c & 1];

    // ---- issue staging for chunk c+1 (hides under this wave's MFMA) ----
    if (c + 1 < NCHUNK) {
      #pragma unroll
      for (int j = 0; j < 2; ++j) {
        const int slot = tid + j * 512;
        load_lds16(K + (size_t)(c + 1) * (CHUNK * DD) + slot * 8,
                   &kbuf[(c + 1) & 1][slot * 8]);
        load_lds16(V + (size_t)(c + 1) * (CHUNK * DD) + slot * 8,
                   &vbuf[(c + 1) & 1][slot * 8]);
      }
    }

    // ---- QK^T: keys [sub*16,+16) x q-half qhf ----
    {
      const int row = sub * 16 + lo16;          // key row within chunk [0,64)
      f32x4 a = {0.f, 0.f, 0.f, 0.f};
      #pragma unroll
      for (int cc = 0; cc < 4; ++cc) {
        const int p = (cc * 4 + g) ^ (row & 7); // swizzled 16B slot
        f16x8 kf = *(const f16x8*)(kb + row * DD + p * 8);
        a = __builtin_amdgcn_mfma_f32_16x16x32_f16(kf, qf[cc], a, 0, 0, 0);
      }
      // D[key][q]: lane holds q=prow, keys sub*16 + g*4 + i
      const int4 mv = *(const int4*)(mrow + c * CHUNK + sub * 16 + g * 4);
      const float e0 = mv.x ? __expf(a[0] - CSHIFT) : 0.f;
      const float e1 = mv.y ? __expf(a[1] - CSHIFT) : 0.f;
      const float e2 = mv.z ? __expf(a[2] - CSHIFT) : 0.f;
      const float e3 = mv.w ? __expf(a[3] - CSHIFT) : 0.f;
      ssum += e0 + e1 + e2 + e3;
      f16x4 eh = { (_Float16)e0, (_Float16)e1, (_Float16)e2, (_Float16)e3 };
      acc_h[c] = eh;
      const int col = sub * 16 + g * 4;         // key col in pbuf row [0,64)
      *(f16x4*)(&pbuf[prow * CHUNK + (((col >> 3) ^ (prow & 7)) << 3) + (col & 7)]) = eh;
    }
    asm volatile("s_waitcnt lgkmcnt(0)" ::: "memory");   // pbuf visible
    block_barrier();                             // barrier 1

    // ---- PV on unnormalized E': d-cols [sub*32,+32) x q-half qhf ----
    {
      #pragma unroll
      for (int t = 0; t < 2; ++t) {
        const int dcol = sub * 32 + t * 16 + lo16;
        #pragma unroll
        for (int ks = 0; ks < 2; ++ks) {
          const int pv_ = (ks * 4 + g) ^ (dcol & 7);
          f16x8 vf = *(const f16x8*)(vb + dcol * CHUNK + pv_ * 8);
          f16x8 pf = *(const f16x8*)(&pbuf[prow * CHUNK + ((ks * 32 + g * 8) ^ ((prow & 7) << 3))]);
          oacc[t] = __builtin_amdgcn_mfma_f32_16x16x32_f16(pf, vf, oacc[t], 0, 0, 0);
        }
      }
    }
    asm volatile("s_waitcnt vmcnt(0)" ::: "memory");     // chunk c+1 landed
    block_barrier();                             // barrier 2
  }

  // ---- Epilogue: denominators, attn from regs, out from oacc ----
  ssum += __shfl_xor(ssum, 16);                 // reduce over g groups
  ssum += __shfl_xor(ssum, 32);
  if (lane < 16) redsum[qhf][lane][sub] = ssum;
  __syncthreads();

  float denom = 0.f;
  #pragma unroll
  for (int j = 0; j < 4; ++j) denom += redsum[qhf][lo16][j];
  const float inv = 1.0f / denom;

  // attn[q0+prow][c*64 + sub*16 + g*4 ..+3] = E' * inv (f32, from registers)
  float* arow = attn + ((size_t)bh * SS + q0 + prow) * SS + sub * 16 + g * 4;
  #pragma unroll
  for (int c = 0; c < NCHUNK; ++c) {
    f32x4 pst = { (float)acc_h[c][0] * inv, (float)acc_h[c][1] * inv,
                  (float)acc_h[c][2] * inv, (float)acc_h[c][3] * inv };
    *(f32x4*)(arow + c * CHUNK) = pst;
  }

  // out: C row = q = qhf*16 + g*4 + i, col = d = sub*32 + t*16 + lo16
  float* O = out + hoff + (size_t)q0 * DD + sub * 32;
  #pragma unroll
  for (int i = 0; i < 4; ++i) {
    const int qr = g * 4 + i;
    float dq = 0.f;
    #pragma unroll
    for (int j = 0; j < 4; ++j) dq += redsum[qhf][qr][j];
    const float rdq = 1.0f / dq;
    #pragma unroll
    for (int t = 0; t < 2; ++t)
      O[(size_t)(qhf * 16 + qr) * DD + t * 16 + lo16] = oacc[t][i] * rdq;
  }
}

extern "C" void kernel_launch(void* const* d_in, const int* in_sizes, int n_in,
                              void* d_out, int out_size, void* d_ws, size_t ws_size,
                              hipStream_t stream) {
  const float* q    = (const float*)d_in[0];
  const float* k    = (const float*)d_in[1];
  const float* v    = (const float*)d_in[2];
  const int*   mask = (const int*)d_in[3];

  const size_t N = (size_t)BB * HH * SS * DD;     // 8388608
  float* out  = (float*)d_out;
  float* attn = out + N;                          // outputs concatenated (out, attn)

  // scratch: 3 f16 tensors = 48 MB
  _Float16* qh  = (_Float16*)d_ws;
  _Float16* kh  = qh + N;
  _Float16* vth = kh + N;

  cvt_f16  <<<N / 8 / 256, 256, 0, stream>>>(q, qh);
  knorm_f16<<<(BB * SS * DD) / 256, 256, 0, stream>>>(k, kh);
  vtrans_f16<<<dim3(DD / 32, SS / 32, BB * HH), dim3(32, 8), 0, stream>>>(v, vth);

  // 64 q-tiles x 32 heads, XCD-swizzled inside the kernel
  attn_fused<<<2048, 512, 0, stream>>>(qh, kh, vth, mask, out, attn);
}